// Round 8
// baseline (145.422 us; speedup 1.0000x reference)
//
#include <hip/hip_runtime.h>
#include <hip/hip_bf16.h>

// Problem constants (fixed by setup_inputs)
#define BATCH    4
#define NPOINT   2048
#define NSUP     16384
#define NCHAN    64
#define NSAMPLE  32
#define R2       0.01f   // f32(0.1*0.1) == f32(0.01)

// ---------------------------------------------------------------------------
// Kernel 1: ball query — one 64-lane wave per query point, 4x ILP unroll.
// 128-thread blocks (2 waves): CDNA caps dispatch at 16 workgroups/CU, so
// 64-thread blocks max out at 16 waves = 50% occupancy (measured 47%).
// 2-wave blocks reach the full 32-wave cap; early-exit imbalance is only
// pairwise.
// d2 uses explicit _rn ops in reference order ((dx^2+dy^2)+dz^2) to avoid
// FMA contraction flipping borderline comparisons.
// ---------------------------------------------------------------------------
struct f3 { float x, y, z; };

__global__ __launch_bounds__(128, 8) void ball_query_kernel(
    const float* __restrict__ query,    // (B, NPOINT, 3)
    const float* __restrict__ support,  // (B, NSUP, 3)
    int* __restrict__ idx_out)          // (B*NPOINT, NSAMPLE)
{
    const int wid  = blockIdx.x * 2 + (threadIdx.x >> 6);  // one wave per query
    const int lane = threadIdx.x & 63;

    const int b = wid >> 11;
    const float* qc = query + (size_t)wid * 3;
    const float qx = qc[0], qy = qc[1], qz = qc[2];

    const float* sup = support + (size_t)b * NSUP * 3;
    int* out = idx_out + ((size_t)wid << 5);

    int cnt = 0;
    int first = 0;
    const unsigned long long ltmask = (lane == 0) ? 0ull : (~0ull >> (64 - lane));

    for (int base = 0; base < NSUP; base += 256) {
        f3 P[4];
#pragma unroll
        for (int u = 0; u < 4; ++u) {
            const int j = base + u * 64 + lane;
            P[u] = *reinterpret_cast<const f3*>(sup + (size_t)j * 3);
        }
        unsigned long long M[4];
#pragma unroll
        for (int u = 0; u < 4; ++u) {
            const float dx = __fsub_rn(qx, P[u].x);
            const float dy = __fsub_rn(qy, P[u].y);
            const float dz = __fsub_rn(qz, P[u].z);
            const float d2 = __fadd_rn(__fadd_rn(__fmul_rn(dx, dx), __fmul_rn(dy, dy)),
                                       __fmul_rn(dz, dz));
            M[u] = __ballot(d2 < R2);
        }
#pragma unroll
        for (int u = 0; u < 4; ++u) {
            const unsigned long long m = M[u];
            if (m) {
                if (cnt == 0) first = base + u * 64 + __builtin_ctzll(m);
                const bool in = (m >> lane) & 1ull;
                const int slot = cnt + __popcll(m & ltmask);
                if (in && slot < NSAMPLE) out[slot] = base + u * 64 + lane;
                cnt += __popcll(m);
            }
        }
        if (cnt >= NSAMPLE) break;
    }
    if (cnt > NSAMPLE) cnt = NSAMPLE;
    if (lane >= cnt && lane < NSAMPLE) out[lane] = (cnt > 0) ? first : 0;
}

// ---------------------------------------------------------------------------
// Kernel 2: fused group — 268 blocks x 1024 threads, 64 KB LDS each.
//  blocks [0,256):   feature gather — stage (b,c) channel row (64 KB) in LDS,
//                    random ds_read_b32 gathers, coalesced float4 stores.
//  blocks [256,268): xyz plane (b,c) — stage support column c (64 KB) in LDS,
//                    query value read direct (L1-broadcast), coalesced stores.
// ---------------------------------------------------------------------------
__global__ __launch_bounds__(1024) void group_all_kernel(
    const float* __restrict__ query,     // (B, NPOINT, 3)
    const float* __restrict__ support,   // (B, NSUP, 3)
    const float* __restrict__ features,  // (B, NCHAN, NSUP)
    const int*   __restrict__ idx,       // (B, NPOINT*NSAMPLE)
    float*       __restrict__ out0,      // (B, 3, NPOINT*NSAMPLE)
    float*       __restrict__ out1)      // (B, NCHAN, NPOINT*NSAMPLE)
{
    __shared__ float lds[NSUP];          // 64 KB
    const int t  = threadIdx.x;
    const int bc = blockIdx.x;

    if (bc < BATCH * NCHAN) {
        // ---- feature path ----
        const int b = bc >> 6;
        const float4* src4 = reinterpret_cast<const float4*>(features + ((size_t)bc << 14));
        float4* row4 = reinterpret_cast<float4*>(lds);
#pragma unroll
        for (int i = 0; i < 4; ++i)
            row4[i * 1024 + t] = src4[i * 1024 + t];
        __syncthreads();

        const int4* idx4 = reinterpret_cast<const int4*>(idx + ((size_t)b << 16));
        float4* dst4 = reinterpret_cast<float4*>(out1 + ((size_t)bc << 16));
#pragma unroll 4
        for (int i = t; i < (NPOINT * NSAMPLE / 4); i += 1024) {
            const int4 id = idx4[i];
            float4 v;
            v.x = lds[id.x];
            v.y = lds[id.y];
            v.z = lds[id.z];
            v.w = lds[id.w];
            dst4[i] = v;
        }
    } else {
        // ---- xyz path ----
        const int j = bc - BATCH * NCHAN;   // 0..11
        const int b = j / 3;
        const int c = j % 3;
        const float* supb = support + (size_t)b * NSUP * 3 + c;
#pragma unroll
        for (int i = 0; i < 16; ++i)
            lds[i * 1024 + t] = supb[(size_t)(i * 1024 + t) * 3];
        __syncthreads();

        const float* qcol = query + (size_t)b * NPOINT * 3 + c;
        const int4* idx4 = reinterpret_cast<const int4*>(idx + ((size_t)b << 16));
        float4* dst4 = reinterpret_cast<float4*>(out0 + ((size_t)j << 16));
#pragma unroll 4
        for (int i = t; i < (NPOINT * NSAMPLE / 4); i += 1024) {
            const int4 id = idx4[i];
            const float qv = qcol[(size_t)(i >> 3) * 3];  // q = (4i)/32 = i/8
            float4 v;
            v.x = __fsub_rn(lds[id.x], qv);
            v.y = __fsub_rn(lds[id.y], qv);
            v.z = __fsub_rn(lds[id.z], qv);
            v.w = __fsub_rn(lds[id.w], qv);
            dst4[i] = v;
        }
    }
}

extern "C" void kernel_launch(void* const* d_in, const int* in_sizes, int n_in,
                              void* d_out, int out_size, void* d_ws, size_t ws_size,
                              hipStream_t stream) {
    const float* query    = (const float*)d_in[0];  // (4,2048,3)
    const float* support  = (const float*)d_in[1];  // (4,16384,3)
    const float* features = (const float*)d_in[2];  // (4,64,16384)

    float* out0 = (float*)d_out;                                 // (4,3,2048,32)
    float* out1 = out0 + (size_t)BATCH * 3 * NPOINT * NSAMPLE;   // (4,64,2048,32)
    int* ws_idx = (int*)d_ws;                                    // (4*2048, 32) = 1 MB

    // two waves per block: 4096 blocks of 128 threads
    ball_query_kernel<<<(BATCH * NPOINT) / 2, 128, 0, stream>>>(query, support, ws_idx);

    // fused grouped_features (256 blocks) + grouped_xyz (12 blocks)
    group_all_kernel<<<BATCH * NCHAN + BATCH * 3, 1024, 0, stream>>>(
        query, support, features, ws_idx, out0, out1);
}

// Round 9
// 144.935 us; speedup vs baseline: 1.0034x; 1.0034x over previous
//
#include <hip/hip_runtime.h>
#include <hip/hip_bf16.h>

// Problem constants (fixed by setup_inputs)
#define BATCH    4
#define NPOINT   2048
#define NSUP     16384
#define NCHAN    64
#define NSAMPLE  32
#define R2       0.01f   // f32(0.1*0.1) == f32(0.01)

// ---------------------------------------------------------------------------
// Kernel 1: ball query — one 64-lane wave per query, 4x ILP + 1-deep software
// prefetch: group k+1's four 64-pt chunk loads issue BEFORE group k's
// ballot/slot compute, hiding the ~200-300cy L2 latency that previously
// serialized every iteration (VALUBusy was 34% because the early-exit break
// blocked cross-iteration load hoisting).
// d2 uses explicit _rn ops in reference order ((dx^2+dy^2)+dz^2) to avoid
// FMA contraction flipping borderline comparisons.
// ---------------------------------------------------------------------------
struct f3 { float x, y, z; };

__global__ __launch_bounds__(128, 8) void ball_query_kernel(
    const float* __restrict__ query,    // (B, NPOINT, 3)
    const float* __restrict__ support,  // (B, NSUP, 3)
    int* __restrict__ idx_out)          // (B*NPOINT, NSAMPLE)
{
    const int wid  = blockIdx.x * 2 + (threadIdx.x >> 6);  // one wave per query
    const int lane = threadIdx.x & 63;

    const int b = wid >> 11;
    const float* qc = query + (size_t)wid * 3;
    const float qx = qc[0], qy = qc[1], qz = qc[2];

    const float* sup = support + (size_t)b * NSUP * 3;
    int* out = idx_out + ((size_t)wid << 5);

    int cnt = 0;
    int first = 0;
    const unsigned long long ltmask = (lane == 0) ? 0ull : (~0ull >> (64 - lane));

    f3 P[4], Pn[4];
#pragma unroll
    for (int u = 0; u < 4; ++u)
        P[u] = *reinterpret_cast<const f3*>(sup + (size_t)(u * 64 + lane) * 3);

    for (int base = 0; base < NSUP; base += 256) {
        const int nbase = base + 256;
        if (nbase < NSUP) {          // wave-uniform guard; issues before compute
#pragma unroll
            for (int u = 0; u < 4; ++u)
                Pn[u] = *reinterpret_cast<const f3*>(
                    sup + (size_t)(nbase + u * 64 + lane) * 3);
        }
        unsigned long long M[4];
#pragma unroll
        for (int u = 0; u < 4; ++u) {
            const float dx = __fsub_rn(qx, P[u].x);
            const float dy = __fsub_rn(qy, P[u].y);
            const float dz = __fsub_rn(qz, P[u].z);
            const float d2 = __fadd_rn(__fadd_rn(__fmul_rn(dx, dx), __fmul_rn(dy, dy)),
                                       __fmul_rn(dz, dz));
            M[u] = __ballot(d2 < R2);
        }
#pragma unroll
        for (int u = 0; u < 4; ++u) {
            const unsigned long long m = M[u];
            if (m) {
                if (cnt == 0) first = base + u * 64 + __builtin_ctzll(m);
                const bool in = (m >> lane) & 1ull;
                const int slot = cnt + __popcll(m & ltmask);
                if (in && slot < NSAMPLE) out[slot] = base + u * 64 + lane;
                cnt += __popcll(m);
            }
        }
        if (cnt >= NSAMPLE) break;
#pragma unroll
        for (int u = 0; u < 4; ++u) P[u] = Pn[u];
    }
    if (cnt > NSAMPLE) cnt = NSAMPLE;
    if (lane >= cnt && lane < NSAMPLE) out[lane] = (cnt > 0) ? first : 0;
}

// ---------------------------------------------------------------------------
// Kernel 2: fused group — exactly 256 blocks x 1024 threads (1/CU, no tail).
// Feature path: stage (b,c) channel row (64 KB) in LDS; ALL 16 idx4 values
// preloaded into registers before the sync (global loads overlap staging),
// so the gather loop is pure ds_read->store with addresses resident.
// xyz epilogue: each block handles 1024 of the 262144 (b,q,s) samples
// directly from L2 (support 192KB/batch resident), 3 coalesced plane stores.
// ---------------------------------------------------------------------------
__global__ __launch_bounds__(1024) void group_all_kernel(
    const float* __restrict__ query,     // (B, NPOINT, 3)
    const float* __restrict__ support,   // (B, NSUP, 3)
    const float* __restrict__ features,  // (B, NCHAN, NSUP)
    const int*   __restrict__ idx,       // (B, NPOINT*NSAMPLE) flat
    float*       __restrict__ out0,      // (B, 3, NPOINT*NSAMPLE)
    float*       __restrict__ out1)      // (B, NCHAN, NPOINT*NSAMPLE)
{
    __shared__ float lds[NSUP];          // 64 KB
    const int t  = threadIdx.x;
    const int bc = blockIdx.x;           // 0..255 = b*NCHAN + c
    const int b  = bc >> 6;

    // stage channel row (coalesced float4)
    const float4* src4 = reinterpret_cast<const float4*>(features + ((size_t)bc << 14));
    float4* row4 = reinterpret_cast<float4*>(lds);
#pragma unroll
    for (int i = 0; i < 4; ++i)
        row4[i * 1024 + t] = src4[i * 1024 + t];

    // preload all idx4 (issues while staging stores drain)
    const int4* idx4 = reinterpret_cast<const int4*>(idx + ((size_t)b << 16));
    int4 id[16];
#pragma unroll
    for (int k = 0; k < 16; ++k)
        id[k] = idx4[k * 1024 + t];

    __syncthreads();

    // gather + coalesced store
    float4* dst4 = reinterpret_cast<float4*>(out1 + ((size_t)bc << 16));
#pragma unroll
    for (int k = 0; k < 16; ++k) {
        float4 v;
        v.x = lds[id[k].x];
        v.y = lds[id[k].y];
        v.z = lds[id[k].z];
        v.w = lds[id[k].w];
        dst4[k * 1024 + t] = v;
    }

    // xyz epilogue: one sample per thread; g in [0, 262144)
    const int g  = bc * 1024 + t;
    const int bb = g >> 16;
    const int qs = g & (NPOINT * NSAMPLE - 1);
    const int q  = qs >> 5;
    const int sid = idx[g];
    const f3 sp = *reinterpret_cast<const f3*>(support + ((size_t)(bb * NSUP + sid)) * 3);
    const f3 qp = *reinterpret_cast<const f3*>(query + ((size_t)(bb * NPOINT + q)) * 3);
    const size_t obase = ((size_t)bb * 3) * (NPOINT * NSAMPLE) + qs;
    out0[obase]                          = __fsub_rn(sp.x, qp.x);
    out0[obase + NPOINT * NSAMPLE]       = __fsub_rn(sp.y, qp.y);
    out0[obase + 2 * NPOINT * NSAMPLE]   = __fsub_rn(sp.z, qp.z);
}

extern "C" void kernel_launch(void* const* d_in, const int* in_sizes, int n_in,
                              void* d_out, int out_size, void* d_ws, size_t ws_size,
                              hipStream_t stream) {
    const float* query    = (const float*)d_in[0];  // (4,2048,3)
    const float* support  = (const float*)d_in[1];  // (4,16384,3)
    const float* features = (const float*)d_in[2];  // (4,64,16384)

    float* out0 = (float*)d_out;                                 // (4,3,2048,32)
    float* out1 = out0 + (size_t)BATCH * 3 * NPOINT * NSAMPLE;   // (4,64,2048,32)
    int* ws_idx = (int*)d_ws;                                    // (4*2048, 32) = 1 MB

    // two waves per block: 4096 blocks of 128 threads
    ball_query_kernel<<<(BATCH * NPOINT) / 2, 128, 0, stream>>>(query, support, ws_idx);

    // fused grouped_features + grouped_xyz: exactly 256 blocks (1 per CU)
    group_all_kernel<<<BATCH * NCHAN, 1024, 0, stream>>>(
        query, support, features, ws_idx, out0, out1);
}